// Round 1
// baseline (698.810 us; speedup 1.0000x reference)
//
#include <hip/hip_runtime.h>
#include <math.h>

#define N_B 2
#define C_CH 256
#define HW_SZ 4096
#define CL_CH 16

__device__ __forceinline__ float tanh_fast(float x){
  float xc = fminf(fmaxf(x, -15.0f), 15.0f);
  float e = __expf(2.0f * xc);
  return (e - 1.0f) / (e + 1.0f);
}

// ---------- Stage-1 conv (C->1): cv[(i*2+n)*HW + q] = dot(f[n,:,q], w_i) + b_i
// grid(64, 2, 2) block 256: 64 q per block, 4 c-groups of 64 reduced via LDS
__global__ void k_conv1(const float* __restrict__ f1, const float* __restrict__ f2,
                        const float* __restrict__ w1, const float* __restrict__ w2,
                        const float* __restrict__ b1, const float* __restrict__ b2,
                        float* __restrict__ cv){
  const int i = blockIdx.z, n = blockIdx.y, t = threadIdx.x;
  const int ql = t & 63, cg = t >> 6;
  const int q = blockIdx.x * 64 + ql;
  const float* f = (i ? f2 : f1) + n * C_CH * HW_SZ;
  const float* w = i ? w2 : w1;
  __shared__ float ws[C_CH];
  __shared__ float red[4][72];
  ws[t] = w[t];
  __syncthreads();
  float acc = 0.f;
  #pragma unroll 8
  for (int c = cg * 64; c < cg * 64 + 64; ++c)
    acc += f[c * HW_SZ + q] * ws[c];
  red[cg][ql] = acc;
  __syncthreads();
  if (t < 64){
    float s = red[0][t] + red[1][t] + red[2][t] + red[3][t] + (i ? b2[0] : b1[0]);
    cv[(i * 2 + n) * HW_SZ + blockIdx.x * 64 + t] = s;
  }
}

// ---------- softmax over 4096 per row; grid(4) block 256
__global__ void k_softmax(const float* __restrict__ cv, float* __restrict__ pr){
  const int r = blockIdx.x, t = threadIdx.x;
  const float* x = cv + r * HW_SZ;
  float* y = pr + r * HW_SZ;
  __shared__ float red[256];
  float v[16];
  float m = -1e30f;
  #pragma unroll
  for (int j = 0; j < 16; j++){ v[j] = x[j * 256 + t]; m = fmaxf(m, v[j]); }
  red[t] = m; __syncthreads();
  for (int s = 128; s > 0; s >>= 1){ if (t < s) red[t] = fmaxf(red[t], red[t + s]); __syncthreads(); }
  m = red[0]; __syncthreads();
  float sum = 0.f;
  #pragma unroll
  for (int j = 0; j < 16; j++){ v[j] = __expf(v[j] - m); sum += v[j]; }
  red[t] = sum; __syncthreads();
  for (int s = 128; s > 0; s >>= 1){ if (t < s) red[t] += red[t + s]; __syncthreads(); }
  const float inv = 1.0f / red[0];
  #pragma unroll
  for (int j = 0; j < 16; j++) y[j * 256 + t] = v[j] * inv;
}

// ---------- fs_i = pr_i * f_i ; cl_i = pw_i @ fs_i + pb_i
// grid(64, 2, 2) block 256
__global__ void k_scale_cl(const float* __restrict__ f1, const float* __restrict__ f2,
                           const float* __restrict__ pr,
                           const float* __restrict__ pw1, const float* __restrict__ pw2,
                           const float* __restrict__ pb1, const float* __restrict__ pb2,
                           float* __restrict__ fs1, float* __restrict__ fs2,
                           float* __restrict__ cl1, float* __restrict__ cl2){
  const int i = blockIdx.z, n = blockIdx.y, t = threadIdx.x;
  const int ql = t & 63, cg = t >> 6;
  const int q = blockIdx.x * 64 + ql;
  const float* f = (i ? f2 : f1) + n * C_CH * HW_SZ;
  float* fs = (i ? fs2 : fs1) + n * C_CH * HW_SZ;
  float* cl = (i ? cl2 : cl1) + n * CL_CH * HW_SZ;
  const float* pw = i ? pw2 : pw1;
  const float* pb = i ? pb2 : pb1;
  __shared__ float wls[CL_CH * C_CH];
  __shared__ float red[4][CL_CH][66];
  #pragma unroll
  for (int j = 0; j < 16; j++) wls[j * 256 + t] = pw[j * 256 + t];
  __syncthreads();
  const float p = pr[(i * 2 + n) * HW_SZ + q];
  float acc[16];
  #pragma unroll
  for (int k = 0; k < 16; k++) acc[k] = 0.f;
  for (int c = cg * 64; c < cg * 64 + 64; ++c){
    float vv = f[c * HW_SZ + q] * p;
    fs[c * HW_SZ + q] = vv;
    #pragma unroll
    for (int k = 0; k < 16; k++) acc[k] += wls[k * 256 + c] * vv;
  }
  #pragma unroll
  for (int k = 0; k < 16; k++) red[cg][k][ql] = acc[k];
  __syncthreads();
  #pragma unroll
  for (int j = 0; j < 4; j++){
    int e = j * 256 + t; int k = e >> 6, qq = e & 63;
    float s = red[0][k][qq] + red[1][k][qq] + red[2][k][qq] + red[3][k][qq];
    cl[k * HW_SZ + blockIdx.x * 64 + qq] = s + pb[k];
  }
}

// ---------- fused hat GEMM: out[c,q] = sum_p src[c,p] * tanh(<u[:,q], v[:,p]>)
//   i=0: src=fs1 u=cl2 v=cl1 out=hat1   (f1_hat[c,q] = sum_p fs1[c,p] A[q,p])
//   i=1: src=fs2 u=cl1 v=cl2 out=hat2   (f2_hat[c,q] = sum_p fs2[c,p] A[p,q])
// grid(64, 2, 2) block 256; per-block output tile 256 x 64, K loop over p in 32-chunks
__global__ __launch_bounds__(256) void k_hat(const float* __restrict__ fs1, const float* __restrict__ fs2,
                      const float* __restrict__ cl1, const float* __restrict__ cl2,
                      float* __restrict__ hat1, float* __restrict__ hat2){
  const int i = blockIdx.z, n = blockIdx.y, t = threadIdx.x;
  const int q0 = blockIdx.x * 64;
  const float* src = (i ? fs2 : fs1) + n * C_CH * HW_SZ;
  const float* u   = (i ? cl1 : cl2) + n * CL_CH * HW_SZ;
  const float* v   = (i ? cl2 : cl1) + n * CL_CH * HW_SZ;
  float* out       = (i ? hat2 : hat1) + n * C_CH * HW_SZ;

  __shared__ float fsT[32][261];  // [pp][c], stride 261 (odd*? -> conflict-free scalar r/w)
  __shared__ float as[32][68];    // a[pp][qq], stride 68 for aligned float4 reads
  __shared__ float us[16][68];    // u block [k][qq]
  __shared__ float vs[16][33];    // v block [k][pp]

  const int lane = t & 31;        // row-group id / pp for a-compute
  const int grp  = t >> 5;        // 0..7
  const int qq0  = grp * 8;

  #pragma unroll
  for (int j = 0; j < 4; j++){
    int e = j * 256 + t; int k = e >> 6, qq = e & 63;
    us[k][qq] = u[k * HW_SZ + q0 + qq];
  }

  float acc[8][8];
  #pragma unroll
  for (int r = 0; r < 8; r++)
    #pragma unroll
    for (int j = 0; j < 8; j++) acc[r][j] = 0.f;

  for (int p0 = 0; p0 < HW_SZ; p0 += 32){
    __syncthreads();   // protect LDS from prev iteration's readers
    // stage v tile [16][32]
    #pragma unroll
    for (int j = 0; j < 2; j++){
      int e = j * 256 + t; int k = e >> 5, pp = e & 31;
      vs[k][pp] = v[k * HW_SZ + p0 + pp];
    }
    // stage src tile transposed: fsT[pp][c]
    #pragma unroll
    for (int j = 0; j < 8; j++){
      int e4 = j * 256 + t; int c = e4 >> 3; int p4 = (e4 & 7) * 4;
      float4 val = *reinterpret_cast<const float4*>(&src[c * HW_SZ + p0 + p4]);
      fsT[p4 + 0][c] = val.x; fsT[p4 + 1][c] = val.y;
      fsT[p4 + 2][c] = val.z; fsT[p4 + 3][c] = val.w;
    }
    __syncthreads();
    // a tile: thread (lane, grp) computes a[lane][qq0..qq0+7]
    float d[8];
    #pragma unroll
    for (int j = 0; j < 8; j++) d[j] = 0.f;
    #pragma unroll
    for (int k = 0; k < 16; k++){
      float vk = vs[k][lane];
      float4 ua = *reinterpret_cast<const float4*>(&us[k][qq0]);
      float4 ub = *reinterpret_cast<const float4*>(&us[k][qq0 + 4]);
      d[0] += vk * ua.x; d[1] += vk * ua.y; d[2] += vk * ua.z; d[3] += vk * ua.w;
      d[4] += vk * ub.x; d[5] += vk * ub.y; d[6] += vk * ub.z; d[7] += vk * ub.w;
    }
    #pragma unroll
    for (int j = 0; j < 8; j++) as[lane][qq0 + j] = tanh_fast(d[j]);
    __syncthreads();
    // main FMA: thread tile = rows {lane+32r} x cols {qq0..qq0+7}
    #pragma unroll 4
    for (int pp = 0; pp < 32; pp++){
      float4 a0 = *reinterpret_cast<const float4*>(&as[pp][qq0]);
      float4 a1 = *reinterpret_cast<const float4*>(&as[pp][qq0 + 4]);
      float av[8] = {a0.x, a0.y, a0.z, a0.w, a1.x, a1.y, a1.z, a1.w};
      float fv[8];
      #pragma unroll
      for (int r = 0; r < 8; r++) fv[r] = fsT[pp][lane + 32 * r];
      #pragma unroll
      for (int r = 0; r < 8; r++){
        #pragma unroll
        for (int j = 0; j < 8; j++) acc[r][j] += fv[r] * av[j];
      }
    }
  }
  #pragma unroll
  for (int r = 0; r < 8; r++){
    float4 o0 = make_float4(acc[r][0], acc[r][1], acc[r][2], acc[r][3]);
    float4 o1 = make_float4(acc[r][4], acc[r][5], acc[r][6], acc[r][7]);
    float* dst = &out[(lane + 32 * r) * HW_SZ + q0 + qq0];
    *reinterpret_cast<float4*>(dst) = o0;
    *reinterpret_cast<float4*>(dst + 4) = o1;
  }
}

// ---------- l2norm(channels) + residual + relu + stage-2 conv
// grid(64, 2, 2) block 256
__global__ void k_norm(const float* __restrict__ hat1, const float* __restrict__ hat2,
                       const float* __restrict__ f1, const float* __restrict__ f2,
                       const float* __restrict__ cw1, const float* __restrict__ cw2,
                       const float* __restrict__ cb1, const float* __restrict__ cb2,
                       float* __restrict__ fp1, float* __restrict__ fp2,
                       float* __restrict__ cv2){
  const int i = blockIdx.z, n = blockIdx.y, t = threadIdx.x;
  const int ql = t & 63, cg = t >> 6;
  const int q = blockIdx.x * 64 + ql;
  const float* hat = (i ? hat2 : hat1) + n * C_CH * HW_SZ;
  const float* f = (i ? f2 : f1) + n * C_CH * HW_SZ;
  float* fp = (i ? fp2 : fp1) + n * C_CH * HW_SZ;
  __shared__ float ws[C_CH];
  __shared__ float red[4][72];
  __shared__ float invs[64];
  ws[t] = (i ? cw2 : cw1)[t];
  __syncthreads();
  float s = 0.f;
  #pragma unroll 8
  for (int c = cg * 64; c < cg * 64 + 64; ++c){ float h = hat[c * HW_SZ + q]; s += h * h; }
  red[cg][ql] = s; __syncthreads();
  if (t < 64){
    float ss = red[0][t] + red[1][t] + red[2][t] + red[3][t];
    invs[t] = 1.0f / fmaxf(sqrtf(ss), 1e-12f);
  }
  __syncthreads();
  const float inv = invs[ql];
  float ca = 0.f;
  #pragma unroll 8
  for (int c = cg * 64; c < cg * 64 + 64; ++c){
    float vv = fmaxf(hat[c * HW_SZ + q] * inv + f[c * HW_SZ + q], 0.0f);
    fp[c * HW_SZ + q] = vv;
    ca += ws[c] * vv;
  }
  red[cg][ql] = ca; __syncthreads();
  if (t < 64){
    float ss = red[0][t] + red[1][t] + red[2][t] + red[3][t] + (i ? cb2[0] : cb1[0]);
    cv2[(i * 2 + n) * HW_SZ + blockIdx.x * 64 + t] = ss;
  }
}

// ---------- final: out_i = pr2_i * fp_i ; grid(2048,1,2) block 256, float4
__global__ void k_final(const float* __restrict__ fp1, const float* __restrict__ fp2,
                        const float* __restrict__ pr2, float* __restrict__ outp){
  const int i = blockIdx.z;
  const int idx4 = (blockIdx.x * 256 + threadIdx.x) * 4;
  const int n = idx4 >> 20;               // C_CH*HW_SZ = 1<<20
  const int q = idx4 & (HW_SZ - 1);
  const float* fp = i ? fp2 : fp1;
  float4 vv = *reinterpret_cast<const float4*>(&fp[idx4]);
  float4 pp = *reinterpret_cast<const float4*>(&pr2[(i * 2 + n) * HW_SZ + q]);
  float4 o; o.x = vv.x * pp.x; o.y = vv.y * pp.y; o.z = vv.z * pp.z; o.w = vv.w * pp.w;
  *reinterpret_cast<float4*>(&outp[i * (C_CH * HW_SZ * N_B) + idx4]) = o;
}

extern "C" void kernel_launch(void* const* d_in, const int* in_sizes, int n_in,
                              void* d_out, int out_size, void* d_ws, size_t ws_size,
                              hipStream_t stream){
  const float* f1  = (const float*)d_in[0];
  const float* f2  = (const float*)d_in[1];
  const float* pw1 = (const float*)d_in[2];
  const float* pb1 = (const float*)d_in[3];
  const float* pw2 = (const float*)d_in[4];
  const float* pb2 = (const float*)d_in[5];
  const float* cw1 = (const float*)d_in[6];
  const float* cb1 = (const float*)d_in[7];
  const float* cw2 = (const float*)d_in[8];
  const float* cb2 = (const float*)d_in[9];
  float* ws = (float*)d_ws;
  // workspace layout (floats); fp reuses fs space (fs dead after k_hat)
  float* FS1  = ws;
  float* FS2  = ws + 2097152;
  float* HAT1 = ws + 4194304;
  float* HAT2 = ws + 6291456;
  float* CL1  = ws + 8388608;
  float* CL2  = ws + 8519680;
  float* CV1  = ws + 8650752;
  float* PR1  = ws + 8667136;
  float* CV2  = ws + 8683520;
  float* PR2  = ws + 8699904;   // total 8,716,288 floats ~= 33.3 MiB
  float* FP1  = FS1;
  float* FP2  = FS2;
  float* outp = (float*)d_out;

  k_conv1   <<<dim3(64, 2, 2), 256, 0, stream>>>(f1, f2, cw1, cw2, cb1, cb2, CV1);
  k_softmax <<<4, 256, 0, stream>>>(CV1, PR1);
  k_scale_cl<<<dim3(64, 2, 2), 256, 0, stream>>>(f1, f2, PR1, pw1, pw2, pb1, pb2,
                                                 FS1, FS2, CL1, CL2);
  k_hat     <<<dim3(64, 2, 2), 256, 0, stream>>>(FS1, FS2, CL1, CL2, HAT1, HAT2);
  k_norm    <<<dim3(64, 2, 2), 256, 0, stream>>>(HAT1, HAT2, f1, f2, cw1, cw2, cb1, cb2,
                                                 FP1, FP2, CV2);
  k_softmax <<<4, 256, 0, stream>>>(CV2, PR2);
  k_final   <<<dim3(2048, 1, 2), 256, 0, stream>>>(FP1, FP2, PR2, outp);
}

// Round 2
// 298.893 us; speedup vs baseline: 2.3380x; 2.3380x over previous
//
#include <hip/hip_runtime.h>
#include <hip/hip_bf16.h>
#include <math.h>

#define N_B 2
#define C_CH 256
#define HW_SZ 4096
#define CL_CH 16

typedef __bf16 bf16x8 __attribute__((ext_vector_type(8)));
typedef float f32x4 __attribute__((ext_vector_type(4)));

__device__ __forceinline__ unsigned short f2bf(float x){
  __hip_bfloat16 b = __float2bfloat16(x);   // RTNE
  return *reinterpret_cast<unsigned short*>(&b);
}

// tanh, NaN-safe at +-inf arguments: 1 - 2/(1+e^{2x})
__device__ __forceinline__ float tanh_fast(float x){
  float e = __expf(2.0f * x);
  return 1.0f - 2.0f / (1.0f + e);
}

// ---------- Stage-1 conv (C->1)
__global__ void k_conv1(const float* __restrict__ f1, const float* __restrict__ f2,
                        const float* __restrict__ w1, const float* __restrict__ w2,
                        const float* __restrict__ b1, const float* __restrict__ b2,
                        float* __restrict__ cv){
  const int i = blockIdx.z, n = blockIdx.y, t = threadIdx.x;
  const int ql = t & 63, cg = t >> 6;
  const int q = blockIdx.x * 64 + ql;
  const float* f = (i ? f2 : f1) + n * C_CH * HW_SZ;
  const float* w = i ? w2 : w1;
  __shared__ float ws[C_CH];
  __shared__ float red[4][72];
  ws[t] = w[t];
  __syncthreads();
  float acc = 0.f;
  #pragma unroll 8
  for (int c = cg * 64; c < cg * 64 + 64; ++c)
    acc += f[c * HW_SZ + q] * ws[c];
  red[cg][ql] = acc;
  __syncthreads();
  if (t < 64){
    float s = red[0][t] + red[1][t] + red[2][t] + red[3][t] + (i ? b2[0] : b1[0]);
    cv[(i * 2 + n) * HW_SZ + blockIdx.x * 64 + t] = s;
  }
}

// ---------- softmax over 4096 per row; grid(4) block 256
__global__ void k_softmax(const float* __restrict__ cv, float* __restrict__ pr){
  const int r = blockIdx.x, t = threadIdx.x;
  const float* x = cv + r * HW_SZ;
  float* y = pr + r * HW_SZ;
  __shared__ float red[256];
  float v[16];
  float m = -1e30f;
  #pragma unroll
  for (int j = 0; j < 16; j++){ v[j] = x[j * 256 + t]; m = fmaxf(m, v[j]); }
  red[t] = m; __syncthreads();
  for (int s = 128; s > 0; s >>= 1){ if (t < s) red[t] = fmaxf(red[t], red[t + s]); __syncthreads(); }
  m = red[0]; __syncthreads();
  float sum = 0.f;
  #pragma unroll
  for (int j = 0; j < 16; j++){ v[j] = __expf(v[j] - m); sum += v[j]; }
  red[t] = sum; __syncthreads();
  for (int s = 128; s > 0; s >>= 1){ if (t < s) red[t] += red[t + s]; __syncthreads(); }
  const float inv = 1.0f / red[0];
  #pragma unroll
  for (int j = 0; j < 16; j++) y[j * 256 + t] = v[j] * inv;
}

// ---------- fs_i = bf16(pr_i * f_i) ; cl_i = pw_i @ (pr*f) + pb_i  (cl in fp32)
__global__ void k_scale_cl(const float* __restrict__ f1, const float* __restrict__ f2,
                           const float* __restrict__ pr,
                           const float* __restrict__ pw1, const float* __restrict__ pw2,
                           const float* __restrict__ pb1, const float* __restrict__ pb2,
                           unsigned short* __restrict__ fs1, unsigned short* __restrict__ fs2,
                           float* __restrict__ cl1, float* __restrict__ cl2){
  const int i = blockIdx.z, n = blockIdx.y, t = threadIdx.x;
  const int ql = t & 63, cg = t >> 6;
  const int q = blockIdx.x * 64 + ql;
  const float* f = (i ? f2 : f1) + n * C_CH * HW_SZ;
  unsigned short* fs = (i ? fs2 : fs1) + n * C_CH * HW_SZ;
  float* cl = (i ? cl2 : cl1) + n * CL_CH * HW_SZ;
  const float* pw = i ? pw2 : pw1;
  const float* pb = i ? pb2 : pb1;
  __shared__ float wls[CL_CH * C_CH];
  __shared__ float red[4][CL_CH][66];
  #pragma unroll
  for (int j = 0; j < 16; j++) wls[j * 256 + t] = pw[j * 256 + t];
  __syncthreads();
  const float p = pr[(i * 2 + n) * HW_SZ + q];
  float acc[16];
  #pragma unroll
  for (int k = 0; k < 16; k++) acc[k] = 0.f;
  for (int c = cg * 64; c < cg * 64 + 64; ++c){
    float vv = f[c * HW_SZ + q] * p;
    fs[c * HW_SZ + q] = f2bf(vv);
    #pragma unroll
    for (int k = 0; k < 16; k++) acc[k] += wls[k * 256 + c] * vv;
  }
  #pragma unroll
  for (int k = 0; k < 16; k++) red[cg][k][ql] = acc[k];
  __syncthreads();
  #pragma unroll
  for (int j = 0; j < 4; j++){
    int e = j * 256 + t; int k = e >> 6, qq = e & 63;
    float s = red[0][k][qq] + red[1][k][qq] + red[2][k][qq] + red[3][k][qq];
    cl[k * HW_SZ + blockIdx.x * 64 + qq] = s + pb[k];
  }
}

// ---------- fused hat GEMM via MFMA.
// out[c,q] = sum_p fs[c,p] * tanh(sum_k v_cl[k,p]*u_cl[k,q])
//   i=0: fs=fs1 u=cl2 v=cl1 -> hat1 ; i=1: fs=fs2 u=cl1 v=cl2 -> hat2
// grid(64 qtiles, 2 c-halves, 4 n*i), block 256 (4 waves).
// Per block: out tile 128c x 64q, K-loop p in 64-chunks.
__global__ __launch_bounds__(256, 2) void k_hat(
    const unsigned short* __restrict__ fs1, const unsigned short* __restrict__ fs2,
    const float* __restrict__ cl1, const float* __restrict__ cl2,
    float* __restrict__ hat1, float* __restrict__ hat2){
  const int t = threadIdx.x;
  const int ni = blockIdx.z, n = ni & 1, i = ni >> 1;
  const int c0 = blockIdx.y * 128;
  const int q0 = blockIdx.x * 64;
  const unsigned short* fs = (i ? fs2 : fs1) + n * C_CH * HW_SZ;
  const float* u = (i ? cl1 : cl2) + n * CL_CH * HW_SZ;  // q-side
  const float* v = (i ? cl2 : cl1) + n * CL_CH * HW_SZ;  // p-side
  float* out = (i ? hat2 : hat1) + n * C_CH * HW_SZ;

  // LDS (ushort strides: fs/a = 72, u/v = 40) — all MFMA frag reads <=2-way banked
  __shared__ __align__(16) unsigned short fsLs[128 * 72];  // fs tile  [cl][p]
  __shared__ __align__(16) unsigned short aLs[64 * 72];    // a tile   [q][p]
  __shared__ __align__(16) unsigned short uLs[64 * 40];    // u        [q][k] (k>=16 zero)
  __shared__ __align__(16) unsigned short vLs[64 * 40];    // v        [p][k] (k>=16 zero)

  const int lane = t & 63, w = t >> 6;
  const int g = lane >> 4, lr = lane & 15;

  // ---- one-time staging: u (bf16, zero-padded k) + zero v's k>=16 region
  for (int e = t; e < 64 * 32; e += 256){
    int q = e & 63, k = e >> 6;
    float val = (k < 16) ? u[k * HW_SZ + q0 + q] : 0.f;
    uLs[q * 40 + k] = f2bf(val);
  }
  for (int e = t; e < 64 * 16; e += 256){
    int p = e & 63, k = 16 + (e >> 6);
    vLs[p * 40 + k] = 0;
  }

  f32x4 acc[2][4];
  #pragma unroll
  for (int cf = 0; cf < 2; ++cf)
    #pragma unroll
    for (int qf = 0; qf < 4; ++qf) acc[cf][qf] = (f32x4){0.f, 0.f, 0.f, 0.f};
  const f32x4 zz = {0.f, 0.f, 0.f, 0.f};

  for (int p0 = 0; p0 < HW_SZ; p0 += 64){
    // issue global loads for this chunk into regs (before barrier)
    uint4 freg[4];
    #pragma unroll
    for (int it = 0; it < 4; ++it){
      int e = it * 256 + t; int cl = e >> 3, jb = e & 7;
      freg[it] = *reinterpret_cast<const uint4*>(&fs[(c0 + cl) * HW_SZ + p0 + jb * 8]);
    }
    float vreg[4];
    #pragma unroll
    for (int it = 0; it < 4; ++it){
      int e = it * 256 + t; int p = e & 63, k = e >> 6;
      vreg[it] = v[k * HW_SZ + p0 + p];
    }
    __syncthreads();  // prior chunk's frag reads done
    #pragma unroll
    for (int it = 0; it < 4; ++it){
      int e = it * 256 + t; int cl = e >> 3, jb = e & 7;
      *reinterpret_cast<uint4*>(&fsLs[cl * 72 + jb * 8]) = freg[it];
    }
    #pragma unroll
    for (int it = 0; it < 4; ++it){
      int e = it * 256 + t; int p = e & 63, k = e >> 6;
      vLs[p * 40 + k] = f2bf(vreg[it]);
    }
    __syncthreads();  // staged tiles visible

    // ---- d-gen: d[p][q] = sum_k v[k,p]*u[k,q] via MFMA (K=16 zero-padded to 32)
    {
      bf16x8 bop = *reinterpret_cast<const bf16x8*>(&uLs[(w * 16 + lr) * 40 + g * 8]);
      #pragma unroll
      for (int pf = 0; pf < 4; ++pf){
        bf16x8 aop = *reinterpret_cast<const bf16x8*>(&vLs[(pf * 16 + lr) * 40 + g * 8]);
        f32x4 dv = __builtin_amdgcn_mfma_f32_16x16x32_bf16(aop, bop, zz, 0, 0, 0);
        unsigned long long pk = 0;
        #pragma unroll
        for (int r = 0; r < 4; ++r){
          float tv = tanh_fast(dv[r]);
          pk |= (unsigned long long)f2bf(tv) << (16 * r);
        }
        // lane holds a[q = 16w+lr][p = pf*16 + 4g + r]
        *reinterpret_cast<unsigned long long*>(&aLs[(w * 16 + lr) * 72 + pf * 16 + g * 4]) = pk;
      }
    }
    __syncthreads();  // a tile visible

    // ---- main MFMA: D[c][q] += fs[c][p] * a[q][p]
    #pragma unroll
    for (int ks = 0; ks < 2; ++ks){
      bf16x8 af[2], bfr[4];
      #pragma unroll
      for (int cf = 0; cf < 2; ++cf)
        af[cf] = *reinterpret_cast<const bf16x8*>(&fsLs[(w * 32 + cf * 16 + lr) * 72 + ks * 32 + g * 8]);
      #pragma unroll
      for (int qf = 0; qf < 4; ++qf)
        bfr[qf] = *reinterpret_cast<const bf16x8*>(&aLs[(qf * 16 + lr) * 72 + ks * 32 + g * 8]);
      #pragma unroll
      for (int cf = 0; cf < 2; ++cf)
        #pragma unroll
        for (int qf = 0; qf < 4; ++qf)
          acc[cf][qf] = __builtin_amdgcn_mfma_f32_16x16x32_bf16(af[cf], bfr[qf], acc[cf][qf], 0, 0, 0);
    }
  }

  // ---- store: lane holds D[c = base + 4g + r][q = base + lr]
  #pragma unroll
  for (int cf = 0; cf < 2; ++cf)
    #pragma unroll
    for (int qf = 0; qf < 4; ++qf){
      #pragma unroll
      for (int r = 0; r < 4; ++r){
        int c = c0 + w * 32 + cf * 16 + g * 4 + r;
        int q = q0 + qf * 16 + lr;
        out[c * HW_SZ + q] = acc[cf][qf][r];
      }
    }
}

// ---------- l2norm(channels) + residual + relu (IN-PLACE into hat) + stage-2 conv
__global__ void k_norm(float* __restrict__ hat1, float* __restrict__ hat2,
                       const float* __restrict__ f1, const float* __restrict__ f2,
                       const float* __restrict__ cw1, const float* __restrict__ cw2,
                       const float* __restrict__ cb1, const float* __restrict__ cb2,
                       float* __restrict__ cv2){
  const int i = blockIdx.z, n = blockIdx.y, t = threadIdx.x;
  const int ql = t & 63, cg = t >> 6;
  const int q = blockIdx.x * 64 + ql;
  float* hat = (i ? hat2 : hat1) + n * C_CH * HW_SZ;
  const float* f = (i ? f2 : f1) + n * C_CH * HW_SZ;
  __shared__ float ws[C_CH];
  __shared__ float red[4][72];
  __shared__ float invs[64];
  ws[t] = (i ? cw2 : cw1)[t];
  __syncthreads();
  float s = 0.f;
  #pragma unroll 8
  for (int c = cg * 64; c < cg * 64 + 64; ++c){ float h = hat[c * HW_SZ + q]; s += h * h; }
  red[cg][ql] = s; __syncthreads();
  if (t < 64){
    float ss = red[0][t] + red[1][t] + red[2][t] + red[3][t];
    invs[t] = 1.0f / fmaxf(sqrtf(ss), 1e-12f);
  }
  __syncthreads();
  const float inv = invs[ql];
  float ca = 0.f;
  #pragma unroll 8
  for (int c = cg * 64; c < cg * 64 + 64; ++c){
    float vv = fmaxf(hat[c * HW_SZ + q] * inv + f[c * HW_SZ + q], 0.0f);
    hat[c * HW_SZ + q] = vv;  // in-place: only this thread touches [c][q]
    ca += ws[c] * vv;
  }
  red[cg][ql] = ca; __syncthreads();
  if (t < 64){
    float ss = red[0][t] + red[1][t] + red[2][t] + red[3][t] + (i ? cb2[0] : cb1[0]);
    cv2[(i * 2 + n) * HW_SZ + blockIdx.x * 64 + t] = ss;
  }
}

// ---------- final: out_i = pr2_i * fp_i
__global__ void k_final(const float* __restrict__ fp1, const float* __restrict__ fp2,
                        const float* __restrict__ pr2, float* __restrict__ outp){
  const int i = blockIdx.z;
  const int idx4 = (blockIdx.x * 256 + threadIdx.x) * 4;
  const int n = idx4 >> 20;
  const int q = idx4 & (HW_SZ - 1);
  const float* fp = i ? fp2 : fp1;
  float4 vv = *reinterpret_cast<const float4*>(&fp[idx4]);
  float4 pp = *reinterpret_cast<const float4*>(&pr2[(i * 2 + n) * HW_SZ + q]);
  float4 o; o.x = vv.x * pp.x; o.y = vv.y * pp.y; o.z = vv.z * pp.z; o.w = vv.w * pp.w;
  *reinterpret_cast<float4*>(&outp[i * (C_CH * HW_SZ * N_B) + idx4]) = o;
}

extern "C" void kernel_launch(void* const* d_in, const int* in_sizes, int n_in,
                              void* d_out, int out_size, void* d_ws, size_t ws_size,
                              hipStream_t stream){
  const float* f1  = (const float*)d_in[0];
  const float* f2  = (const float*)d_in[1];
  const float* pw1 = (const float*)d_in[2];
  const float* pb1 = (const float*)d_in[3];
  const float* pw2 = (const float*)d_in[4];
  const float* pb2 = (const float*)d_in[5];
  const float* cw1 = (const float*)d_in[6];
  const float* cb1 = (const float*)d_in[7];
  const float* cw2 = (const float*)d_in[8];
  const float* cb2 = (const float*)d_in[9];
  float* ws = (float*)d_ws;
  // layout (float offsets): HAT doubles as FP (k_norm in-place, k_final reads it)
  float* HAT1 = ws;                               // 2,097,152 floats
  float* HAT2 = ws + 2097152;
  unsigned short* FS1 = (unsigned short*)(ws + 4194304);  // bf16, 2,097,152 shorts
  unsigned short* FS2 = (unsigned short*)(ws + 5242880);
  float* CL1  = ws + 6291456;                     // 131,072 floats
  float* CL2  = ws + 6422528;
  float* CV1  = ws + 6553600;
  float* PR1  = ws + 6569984;
  float* CV2  = ws + 6586368;
  float* PR2  = ws + 6602752;                     // end 6,619,136 floats ~= 25.2 MiB
  float* outp = (float*)d_out;

  k_conv1   <<<dim3(64, 2, 2), 256, 0, stream>>>(f1, f2, cw1, cw2, cb1, cb2, CV1);
  k_softmax <<<4, 256, 0, stream>>>(CV1, PR1);
  k_scale_cl<<<dim3(64, 2, 2), 256, 0, stream>>>(f1, f2, PR1, pw1, pw2, pb1, pb2,
                                                 FS1, FS2, CL1, CL2);
  k_hat     <<<dim3(64, 2, 4), 256, 0, stream>>>(FS1, FS2, CL1, CL2, HAT1, HAT2);
  k_norm    <<<dim3(64, 2, 2), 256, 0, stream>>>(HAT1, HAT2, f1, f2, cw1, cw2, cb1, cb2, CV2);
  k_softmax <<<4, 256, 0, stream>>>(CV2, PR2);
  k_final   <<<dim3(2048, 1, 2), 256, 0, stream>>>(HAT1, HAT2, PR2, outp);
}